// Round 2
// 337.357 us; speedup vs baseline: 1.0033x; 1.0033x over previous
//
#include <hip/hip_runtime.h>
#include <math.h>

// dca_layer: out = x * (1 + sigmoid(max over spatial dims of x per (b,c) plane))
// The two channel_shuffles (g=16 then g=32 on c=512) are exact inverse
// permutations -> identity.
//
// x: [32, 512, 56, 56] fp32 -> 16384 planes x 3136 floats. 3136 = 49 floats
// per lane exactly: 12 unconditional float4 rounds (3072 floats) + 1 scalar
// float (last 64). One 64-lane wave per plane, whole plane register-resident,
// shfl_xor max reduce, scale, coalesced write-back.
//
// Traffic: 205.5 MB rd + 205.5 MB wr = 411 MB -> ~65 us floor at 6.3 TB/s.
// Round-0 counters: kernel absent from top-5 (all harness fills @ ~125 us)
// -> kernel < 125 us; remaining gap is streaming efficiency, not traffic.
// This round:
//  - exact 49-float/lane split (no masked tail round, -4 VGPR, no exec churn)
//  - __launch_bounds__(256, 8): 49 data VGPRs + temps fits 64 -> 8 waves/EU
//    (was ~7) for deeper vmcnt-drain hiding
//  - nontemporal load/store: stream-once data, skip L2/L3 allocate (the
//    inter-iteration 784 MiB poison fill flushes caches anyway)
//  - round-1 fix: __builtin_nontemporal_* requires a clang ext_vector_type,
//    not HIP's float4 struct -> use float __attribute__((ext_vector_type(4))).

#define PLANE_ELEMS 3136
#define R4 12                 // 12 full float4 rounds = 3072 floats
#define TAIL_BASE 3072        // + lane -> floats 3072..3135
#define PLANES_PER_BLOCK 4    // 4 waves per 256-thread block

typedef float f4 __attribute__((ext_vector_type(4)));

__global__ __launch_bounds__(256, 8) void dca_gate_kernel(
        const float* __restrict__ x,
        float* __restrict__ out) {
    const int lane  = threadIdx.x & 63;
    const int wave  = threadIdx.x >> 6;
    const int plane = blockIdx.x * PLANES_PER_BLOCK + wave;

    const float* __restrict__ sp = x   + (size_t)plane * PLANE_ELEMS;
    float*       __restrict__ dp = out + (size_t)plane * PLANE_ELEMS;
    const f4* __restrict__ src = (const f4*)sp;
    f4*       __restrict__ dst = (f4*)dp;

    f4 v[R4];

    // Load entire plane into this wave's registers. All rounds unconditional,
    // all 64 lanes active every round.
#pragma unroll
    for (int r = 0; r < R4; ++r)
        v[r] = __builtin_nontemporal_load(&src[r * 64 + lane]);
    float tail = __builtin_nontemporal_load(&sp[TAIL_BASE + lane]);

    // Per-lane max over the 49 held floats (compiler fuses to v_max3 chains).
    float m = tail;
#pragma unroll
    for (int r = 0; r < R4; ++r)
        m = fmaxf(m, fmaxf(fmaxf(v[r].x, v[r].y), fmaxf(v[r].z, v[r].w)));

    // Wave-wide max reduction (64 lanes).
#pragma unroll
    for (int off = 32; off > 0; off >>= 1)
        m = fmaxf(m, __shfl_xor(m, off, 64));

    // gate = sigmoid(plane_max); out = x * (1 + gate)
    const float s = 1.0f + 1.0f / (1.0f + __expf(-m));

    // Scale the register-held plane and stream it out.
#pragma unroll
    for (int r = 0; r < R4; ++r) {
        f4 o = v[r] * s;
        __builtin_nontemporal_store(o, &dst[r * 64 + lane]);
    }
    __builtin_nontemporal_store(tail * s, &dp[TAIL_BASE + lane]);
}

extern "C" void kernel_launch(void* const* d_in, const int* in_sizes, int n_in,
                              void* d_out, int out_size, void* d_ws, size_t ws_size,
                              hipStream_t stream) {
    const float* x = (const float*)d_in[0];
    float* out = (float*)d_out;
    // 16384 planes / 4 planes per block
    dim3 grid(4096), block(256);
    dca_gate_kernel<<<grid, block, 0, stream>>>(x, out);
}